// Round 5
// baseline (191.314 us; speedup 1.0000x reference)
//
#include <hip/hip_runtime.h>
#include <hip/hip_bf16.h>

#define MDIM 4096
#define DDIM 2048
#define HDIM 2048
#define EDIM 8

typedef float v4f __attribute__((ext_vector_type(4)));
typedef int   v4i __attribute__((ext_vector_type(4)));
typedef int   v8i __attribute__((ext_vector_type(8)));

// async global->LDS, 16B per lane. lds pointer must be wave-uniform
// (HW writes base + lane*16).
__device__ __forceinline__ void gl2lds16(const void* g, void* l) {
  __builtin_amdgcn_global_load_lds(
      (const __attribute__((address_space(1))) void*)g,
      (__attribute__((address_space(3))) void*)l,
      16, 0, 0);
}

// ---------------- Kernel 1: gating softmax + fp8 quantize of x ----------------
__global__ __launch_bounds__(256) void k_gate_xq(
    const float* __restrict__ x, const float* __restrict__ gw,
    const float* __restrict__ gb, float* __restrict__ gate,
    unsigned char* __restrict__ x8)
{
  const int wid  = threadIdx.x >> 6;
  const int lane = threadIdx.x & 63;
  const int m    = blockIdx.x * 4 + wid;

  const float4* xr = (const float4*)(x + (size_t)m * DDIM);
  unsigned int* qr = (unsigned int*)(x8 + (size_t)m * DDIM);

  float part[EDIM];
#pragma unroll
  for (int e = 0; e < EDIM; ++e) part[e] = 0.f;

#pragma unroll
  for (int it = 0; it < DDIM / 4 / 64; ++it) {   // 8 iterations
    const int idx = it * 64 + lane;
    const float4 xv = xr[idx];
    int pk = __builtin_amdgcn_cvt_pk_fp8_f32(xv.x, xv.y, 0, false);
    pk = __builtin_amdgcn_cvt_pk_fp8_f32(xv.z, xv.w, pk, true);
    qr[idx] = (unsigned int)pk;
#pragma unroll
    for (int e = 0; e < EDIM; ++e) {
      const float4 wv = ((const float4*)(gw + (size_t)e * DDIM))[idx];
      part[e] += xv.x * wv.x + xv.y * wv.y + xv.z * wv.z + xv.w * wv.w;
    }
  }
#pragma unroll
  for (int e = 0; e < EDIM; ++e) {
#pragma unroll
    for (int off = 32; off > 0; off >>= 1)
      part[e] += __shfl_xor(part[e], off);
  }
  float lg[EDIM];
  float s = 0.f;
#pragma unroll
  for (int e = 0; e < EDIM; ++e) lg[e] = part[e] + gb[e];
  float mx = lg[0];
#pragma unroll
  for (int e = 1; e < EDIM; ++e) mx = fmaxf(mx, lg[e]);
#pragma unroll
  for (int e = 0; e < EDIM; ++e) { lg[e] = expf(lg[e] - mx); s += lg[e]; }
  const float inv = 1.f / s;
  if (lane < EDIM) gate[m * EDIM + lane] = lg[lane] * inv;
}

// ---------------- Kernel 2: fp8 quantize of expert_w --------------------------
__global__ void k_wq(const float* __restrict__ w, unsigned char* __restrict__ w8)
{
  const long long n4 = (long long)EDIM * HDIM * DDIM / 4;
  const long long stride = (long long)gridDim.x * blockDim.x;
  for (long long i = (long long)blockIdx.x * blockDim.x + threadIdx.x; i < n4;
       i += stride) {
    const float4 v = ((const float4*)w)[i];
    int pk = __builtin_amdgcn_cvt_pk_fp8_f32(v.x, v.y, 0, false);
    pk = __builtin_amdgcn_cvt_pk_fp8_f32(v.z, v.w, pk, true);
    ((unsigned int*)w8)[i] = (unsigned int)pk;
  }
}

// ---------------- Kernel 3: fused grouped GEMM + gated combine ----------------
// 512 threads (8 waves, 4m x 2n), tile 256x128, BK=128 fp8 bytes, per-wave
// 64x64 output. MX-scaled MFMA 16x16x128 fp8/fp8 with unit e8m0 scales.
// T2 XOR-swizzle both-sides. T3+T4: 3 LDS buffers (48 KB each), 2-deep
// prefetch, counted s_waitcnt vmcnt(12) (never 0 in main loop), raw barriers.
// T5 setprio around the MFMA cluster. Gates pre-cached in LDS so the per-
// expert epilogue never touches vmcnt. T1 XCD-chunked block mapping.
__global__ __launch_bounds__(512, 2) void k_moe_gemm(
    const unsigned char* __restrict__ x8,   // [M, D]
    const unsigned char* __restrict__ w8,   // [E, H, D]
    const float* __restrict__ gate,         // [M, 8]
    float* __restrict__ out)                // [M, H] f32
{
  extern __shared__ unsigned char smem[];   // 3*49152 + 8192 = 155648 B

  const int tid  = threadIdx.x;
  const int lane = tid & 63;
  const int wid  = tid >> 6;
  const int wm   = wid >> 1;        // 0..3
  const int wn   = wid & 1;         // 0..1

  // XCD-aware chunking: 256 blocks, xcd = bid&7; each XCD owns a 4x8
  // square of (m,h) tiles (m-tiles 16, n-tiles 16; bijective).
  const int bid   = blockIdx.x;
  const int xcd   = bid & 7;
  const int local = bid >> 3;                        // 0..31
  const int tm    = (xcd >> 1) * 4 + (local >> 3);   // 0..15
  const int tn    = (xcd & 1) * 8 + (local & 7);     // 0..15
  const int bm    = tm * 256;
  const int bn    = tn * 128;

  const int lrow = lane & 15;
  const int lk   = lane >> 4;             // 0..3 -> k-block of 32 bytes
  const int swz  = (lrow & 7) << 4;       // read-side XOR
  const int c0   = (lk * 32) ^ swz;       // first 16B chunk (swizzled)
  const int c1   = (lk * 32 + 16) ^ swz;  // second 16B chunk (swizzled)

  float* sG = (float*)(smem + 3 * 49152); // [256][8] gate cache

  // staging source bases (k0 = 0). row(i) = i*64 + (tid>>3); inverse-swz col.
  const int strow = tid >> 3;
  const int stcol = ((tid & 7) * 16) ^ ((strow & 7) << 4);
  const unsigned char* abase[4];
  const unsigned char* bbase[2];
#pragma unroll
  for (int i = 0; i < 4; ++i)
    abase[i] = x8 + (size_t)(bm + i * 64 + strow) * DDIM + stcol;
#pragma unroll
  for (int i = 0; i < 2; ++i)
    bbase[i] = w8 + (size_t)(bn + i * 64 + strow) * DDIM + stcol;

  v4f outacc[4][4];
  v4f acc[4][4];
#pragma unroll
  for (int i = 0; i < 4; ++i)
#pragma unroll
    for (int j = 0; j < 4; ++j) {
      outacc[i][j][0] = 0.f; outacc[i][j][1] = 0.f;
      outacc[i][j][2] = 0.f; outacc[i][j][3] = 0.f;
      acc[i][j][0] = 0.f; acc[i][j][1] = 0.f;
      acc[i][j][2] = 0.f; acc[i][j][3] = 0.f;
    }

#define STAGE(IT, BUF) do {                                                    \
    const int e_ = (IT) >> 4;                                                  \
    const int k_ = ((IT) & 15) * 128;                                          \
    const size_t boff_ = (size_t)e_ * ((size_t)HDIM * DDIM) + k_;              \
    unsigned char* la_ = smem + (BUF) * 49152;                                 \
    unsigned char* lb_ = la_ + 32768;                                          \
    _Pragma("unroll") for (int i = 0; i < 4; ++i)                              \
      gl2lds16(abase[i] + k_, (void*)(la_ + i * 8192 + wid * 1024));           \
    _Pragma("unroll") for (int i = 0; i < 2; ++i)                              \
      gl2lds16(bbase[i] + boff_, (void*)(lb_ + i * 8192 + wid * 1024));        \
  } while (0)

#define COMP(BUF, T) do {                                                      \
    const unsigned char* pA_ = smem + (BUF) * 49152 +                          \
                               (size_t)(wm * 64 + lrow) * 128;                 \
    const unsigned char* pB_ = smem + (BUF) * 49152 + 32768 +                  \
                               (size_t)(wn * 64 + lrow) * 128;                 \
    v8i av_[4];                                                                \
    _Pragma("unroll") for (int f = 0; f < 4; ++f) {                            \
      union { v8i v; v4i h[2]; } u_;                                           \
      u_.h[0] = *(const v4i*)(pA_ + f * 2048 + c0);                            \
      u_.h[1] = *(const v4i*)(pA_ + f * 2048 + c1);                            \
      av_[f] = u_.v;                                                           \
    }                                                                          \
    __builtin_amdgcn_s_setprio(1);                                             \
    _Pragma("unroll") for (int j = 0; j < 4; ++j) {                            \
      union { v8i v; v4i h[2]; } u_;                                           \
      u_.h[0] = *(const v4i*)(pB_ + j * 2048 + c0);                            \
      u_.h[1] = *(const v4i*)(pB_ + j * 2048 + c1);                            \
      const v8i bv_ = u_.v;                                                    \
      _Pragma("unroll") for (int i = 0; i < 4; ++i)                            \
        acc[i][j] = __builtin_amdgcn_mfma_scale_f32_16x16x128_f8f6f4(          \
            av_[i], bv_, acc[i][j], 0 /*fp8*/, 0 /*fp8*/,                      \
            0, 127 /*e8m0 1.0*/, 0, 127 /*e8m0 1.0*/);                         \
    }                                                                          \
    __builtin_amdgcn_s_setprio(0);                                             \
    if (((T) & 15) == 15) {                                                    \
      const int e_ = (T) >> 4;                                                 \
      _Pragma("unroll") for (int i = 0; i < 4; ++i)                            \
        _Pragma("unroll") for (int q = 0; q < 4; ++q) {                        \
          const float g_ = sG[(wm * 64 + i * 16 + lk * 4 + q) * 8 + e_];       \
          _Pragma("unroll") for (int j = 0; j < 4; ++j) {                      \
            const float yb_ =                                                  \
                __bfloat162float(__float2bfloat16(acc[i][j][q]));              \
            outacc[i][j][q] += g_ * yb_;                                       \
            acc[i][j][q] = 0.f;                                                \
          }                                                                    \
        }                                                                      \
    }                                                                          \
  } while (0)

#define STEP(T, BUF, SBUF, WAIT) do {                                          \
    if ((T) + 2 < 128) STAGE((T) + 2, (SBUF));                                 \
    asm volatile("s_waitcnt vmcnt(" #WAIT ")" ::: "memory");                   \
    __builtin_amdgcn_s_barrier();                                              \
    __builtin_amdgcn_sched_barrier(0);                                         \
    COMP((BUF), (T));                                                          \
    __builtin_amdgcn_sched_barrier(0);                                         \
    __builtin_amdgcn_s_barrier();                                              \
  } while (0)

  // ---- prologue: gate cache + stage tiles 0,1
  {
    const float4 gv = *(const float4*)(gate + (size_t)bm * EDIM + tid * 4);
    ((float4*)sG)[tid] = gv;
  }
  STAGE(0, 0);
  STAGE(1, 1);
  __syncthreads();   // drains prologue loads + makes sG visible (once)

  // ---- main loop: tiles 0..125, buffers t%3, 2-deep prefetch, vmcnt(12)
  for (int t0 = 0; t0 < 126; t0 += 3) {
    STEP(t0 + 0, 0, 2, 12);
    STEP(t0 + 1, 1, 0, 12);
    STEP(t0 + 2, 2, 1, 12);
  }
  // ---- tail: tiles 126 (buf0), 127 (buf1); drain counts 6 -> 0
  STEP(126, 0, 2, 6);
  STEP(127, 1, 2, 0);

#undef STEP
#undef COMP
#undef STAGE

  // write out[m, h] (f32), coalesced across the 16 lanes of each row group
#pragma unroll
  for (int i = 0; i < 4; ++i)
#pragma unroll
    for (int q = 0; q < 4; ++q) {
      const size_t r = (size_t)(bm + wm * 64 + i * 16 + lk * 4 + q);
      float* orow = out + r * HDIM + bn + wn * 64 + lrow;
#pragma unroll
      for (int j = 0; j < 4; ++j)
        orow[j * 16] = outacc[i][j][q];
    }
}

extern "C" void kernel_launch(void* const* d_in, const int* in_sizes, int n_in,
                              void* d_out, int out_size, void* d_ws, size_t ws_size,
                              hipStream_t stream) {
  (void)in_sizes; (void)n_in; (void)out_size; (void)ws_size;
  const float* x        = (const float*)d_in[0];
  const float* gate_w   = (const float*)d_in[1];
  const float* gate_b   = (const float*)d_in[2];
  const float* expert_w = (const float*)d_in[3];
  float* out = (float*)d_out;

  char* ws = (char*)d_ws;
  float* gate       = (float*)ws;                                   // 131072 B
  unsigned char* x8 = (unsigned char*)(ws + 131072);                // 8 MiB
  unsigned char* w8 = (unsigned char*)(ws + 131072 + (size_t)MDIM * DDIM);

  hipLaunchKernelGGL(k_gate_xq, dim3(MDIM / 4), dim3(256), 0, stream,
                     x, gate_w, gate_b, gate, x8);
  hipLaunchKernelGGL(k_wq, dim3(4096), dim3(256), 0, stream, expert_w, w8);
  hipLaunchKernelGGL(k_moe_gemm, dim3(256), dim3(512),
                     3 * 49152 + 8192, stream, x8, w8, gate, out);
}